// Round 1
// baseline (564.868 us; speedup 1.0000x reference)
//
#include <hip/hip_runtime.h>
#include <hip/hip_bf16.h>
#include <math.h>

// Dual-attention block, bf16 MFMA implementation.
// ws layout (needs ~60 MB):
//   [0,4MB)    bf16 transposed weights: qkvT_t[1536][512], oT_t[512][512], qkvT_g, oT_g
//   [4,12)     normed bf16 [8192][512]        (reused stage2)
//   [12,20)    q bf16                          (reused qg)
//   [20,28)    k bf16                          (reused kg)
//   [28,36)    v (time: transposed [bh][d][t]) (reused vg, untransposed)
//   [36,44)    ctx bf16 [B][T][512]            (reused ctx_g [T*B][512])
//   [44,60)    h2 fp32 [B][T][512]

typedef __bf16 bf16x8 __attribute__((ext_vector_type(8)));
typedef __bf16 bf16x4 __attribute__((ext_vector_type(4)));
typedef float  f32x4  __attribute__((ext_vector_type(4)));

#define LN1E4_OVER_32 0.2878231366242558f

// ---------------- weight convert + transpose: wt[n][k] = w[k][n] (bf16) ----------------
__global__ __launch_bounds__(256) void transpose_w(
    const float* w0, const float* w1, const float* w2, const float* w3,
    const float* w4, const float* w5, const float* w6, const float* w7,
    __bf16* qkvT_t, __bf16* oT_t, __bf16* qkvT_g, __bf16* oT_g)
{
    int mat = blockIdx.z;
    const float* src; __bf16* dst; int rowOff;
    switch (mat) {
        case 0: src=w0; dst=qkvT_t; rowOff=0;    break;
        case 1: src=w1; dst=qkvT_t; rowOff=512;  break;
        case 2: src=w2; dst=qkvT_t; rowOff=1024; break;
        case 3: src=w3; dst=oT_t;   rowOff=0;    break;
        case 4: src=w4; dst=qkvT_g; rowOff=0;    break;
        case 5: src=w5; dst=qkvT_g; rowOff=512;  break;
        case 6: src=w6; dst=qkvT_g; rowOff=1024; break;
        default: src=w7; dst=oT_g;  rowOff=0;    break;
    }
    __shared__ float tile[32][33];
    int n0 = blockIdx.x * 32, k0 = blockIdx.y * 32;
    int tt = threadIdx.x;
    int kr = tt >> 3, nc = (tt & 7) * 4;
    float4 v = *(const float4*)(src + (size_t)(k0 + kr) * 512 + n0 + nc);
    tile[kr][nc+0] = v.x; tile[kr][nc+1] = v.y; tile[kr][nc+2] = v.z; tile[kr][nc+3] = v.w;
    __syncthreads();
    int nr = tt >> 3, kc = (tt & 7) * 4;
    bf16x4 o;
    o[0] = (__bf16)tile[kc+0][nr]; o[1] = (__bf16)tile[kc+1][nr];
    o[2] = (__bf16)tile[kc+2][nr]; o[3] = (__bf16)tile[kc+3][nr];
    *(bf16x4*)(dst + (size_t)(rowOff + n0 + nr) * 512 + k0 + kc) = o;
}

// ---------------- RMSNorm rows of 512, fp32 in -> bf16 out; optional (b,t)->(t,b) remap ----------------
__global__ __launch_bounds__(256) void rmsnorm_k(
    const float* __restrict__ x, const float* __restrict__ w,
    __bf16* __restrict__ y, int remap)
{
    int row = blockIdx.x * 4 + (threadIdx.x >> 6);
    int l = threadIdx.x & 63;
    const float* xr = x + (size_t)row * 512 + l * 8;
    float4 a = *(const float4*)xr;
    float4 b = *(const float4*)(xr + 4);
    float ss = a.x*a.x + a.y*a.y + a.z*a.z + a.w*a.w
             + b.x*b.x + b.y*b.y + b.z*b.z + b.w*b.w;
    for (int m = 1; m < 64; m <<= 1) ss += __shfl_xor(ss, m);
    float rms = rsqrtf(ss * (1.0f / 512.0f) + 1e-6f);
    float4 wa = *(const float4*)(w + l * 8);
    float4 wb = *(const float4*)(w + l * 8 + 4);
    int orow = remap ? ((row & 1023) * 8 + (row >> 10)) : row;
    bf16x8 o;
    o[0] = (__bf16)(a.x * rms * wa.x); o[1] = (__bf16)(a.y * rms * wa.y);
    o[2] = (__bf16)(a.z * rms * wa.z); o[3] = (__bf16)(a.w * rms * wa.w);
    o[4] = (__bf16)(b.x * rms * wb.x); o[5] = (__bf16)(b.y * rms * wb.y);
    o[6] = (__bf16)(b.z * rms * wb.z); o[7] = (__bf16)(b.w * rms * wb.w);
    *(bf16x8*)(y + (size_t)orow * 512 + l * 8) = o;
}

// ---------------- 128x128 bf16 MFMA GEMM with fused epilogues ----------------
// mode 0: QKV time  — RoPE on q,k (q *= 0.125), scatter q/k[bh][t][d], vt[bh][d][t]
// mode 1: O time    — out fp32 = acc + resid (rows direct)
// mode 2: QKV group — scatter q/k/v [t][h][b][d] (q *= 0.125)
// mode 3: O group   — rows m=(t,b) remapped to (b,t) for resid/out
__global__ __launch_bounds__(256) void gemm_ep(
    const __bf16* __restrict__ A, const __bf16* __restrict__ Bt,
    const int* __restrict__ pos, const float* __restrict__ resid,
    float* __restrict__ outF,
    __bf16* __restrict__ o0, __bf16* __restrict__ o1, __bf16* __restrict__ o2,
    int mode)
{
    __shared__ __bf16 As[128 * 32];
    __shared__ __bf16 Bs[128 * 32];
    int l = threadIdx.x & 63, w = threadIdx.x >> 6;
    int l16 = l & 15, quad = l >> 4;
    int wm = w >> 1, wn = w & 1;
    int mblk = blockIdx.y * 128, nblk = blockIdx.x * 128;
    f32x4 acc[4][4] = {};

    for (int k0 = 0; k0 < 512; k0 += 32) {
        __syncthreads();
        #pragma unroll
        for (int it = 0; it < 2; ++it) {
            int c = threadIdx.x + it * 256;
            int row = c >> 2, col = (c & 3) << 3;
            *(bf16x8*)(As + c * 8) = *(const bf16x8*)(A  + (size_t)(mblk + row) * 512 + k0 + col);
            *(bf16x8*)(Bs + c * 8) = *(const bf16x8*)(Bt + (size_t)(nblk + row) * 512 + k0 + col);
        }
        __syncthreads();
        bf16x8 aF[4], bF[4];
        #pragma unroll
        for (int mt = 0; mt < 4; mt++) aF[mt] = *(bf16x8*)(As + (wm * 64 + mt * 16 + l16) * 32 + quad * 8);
        #pragma unroll
        for (int nt = 0; nt < 4; nt++) bF[nt] = *(bf16x8*)(Bs + (wn * 64 + nt * 16 + l16) * 32 + quad * 8);
        #pragma unroll
        for (int mt = 0; mt < 4; mt++)
            #pragma unroll
            for (int nt = 0; nt < 4; nt++)
                acc[mt][nt] = __builtin_amdgcn_mfma_f32_16x16x32_bf16(aF[mt], bF[nt], acc[mt][nt], 0, 0, 0);
    }

    int colbase = nblk + wn * 64;   // 64-aligned -> wave covers exactly one head of one matrix
    if (mode == 0 || mode == 2) {
        int mat = colbase >> 9;             // 0=q 1=k 2=v (uniform)
        int hh  = (colbase & 511) >> 6;     // head (uniform)
        __bf16* dst = (mat == 0) ? o0 : (mat == 1) ? o1 : o2;
        bool isQ = (mat == 0), isV = (mat == 2);
        #pragma unroll
        for (int mt = 0; mt < 4; mt++) {
            #pragma unroll
            for (int r = 0; r < 4; r++) {
                int grow = mblk + wm * 64 + mt * 16 + quad * 4 + r;
                if (mode == 0) {
                    int b = grow >> 10, t = grow & 1023;
                    if (!isV) {
                        int p = pos[grow];
                        #pragma unroll
                        for (int nt = 0; nt < 2; nt++) {
                            int i = nt * 16 + l16;                  // d%32
                            float ang = (float)p * __expf((float)i * -LN1E4_OVER_32);
                            float c, s; sincosf(ang, &s, &c);
                            float x1 = acc[mt][nt][r], x2 = acc[mt][nt + 2][r];
                            float y1 = x1 * c - x2 * s;
                            float y2 = x2 * c + x1 * s;
                            if (isQ) { y1 *= 0.125f; y2 *= 0.125f; }
                            size_t base = ((size_t)(b * 8 + hh) * 1024 + t) * 64;
                            dst[base + i]      = (__bf16)y1;
                            dst[base + i + 32] = (__bf16)y2;
                        }
                    } else {
                        #pragma unroll
                        for (int nt = 0; nt < 4; nt++) {
                            int d = nt * 16 + l16;
                            dst[((size_t)(b * 8 + hh) * 64 + d) * 1024 + t] = (__bf16)acc[mt][nt][r];
                        }
                    }
                } else { // mode 2
                    int t = grow >> 3, b = grow & 7;
                    size_t base = (((size_t)t * 8 + hh) * 8 + b) * 64;
                    #pragma unroll
                    for (int nt = 0; nt < 4; nt++) {
                        float v = acc[mt][nt][r];
                        if (isQ) v *= 0.125f;
                        dst[base + nt * 16 + l16] = (__bf16)v;
                    }
                }
            }
        }
    } else { // mode 1 / 3: O-projection + residual, fp32 out
        #pragma unroll
        for (int mt = 0; mt < 4; mt++)
            #pragma unroll
            for (int r = 0; r < 4; r++) {
                int grow = mblk + wm * 64 + mt * 16 + quad * 4 + r;
                int orow = (mode == 3) ? (((grow & 7) << 10) + (grow >> 3)) : grow;
                #pragma unroll
                for (int nt = 0; nt < 4; nt++) {
                    int col = colbase + nt * 16 + l16;
                    size_t oi = (size_t)orow * 512 + col;
                    outF[oi] = acc[mt][nt][r] + resid[oi];
                }
            }
    }
}

// ---------------- flash attention (time axis): per block 64 q-rows of one (b,h) ----------------
__global__ __launch_bounds__(256) void flash_t(
    const __bf16* __restrict__ q, const __bf16* __restrict__ k,
    const __bf16* __restrict__ vt, const float* __restrict__ tmask,
    __bf16* __restrict__ ctx)
{
    int bh = blockIdx.y;
    int w = threadIdx.x >> 6, l = threadIdx.x & 63;
    int l16 = l & 15, quad = l >> 4;
    int q0 = blockIdx.x * 64 + w * 16;

    __shared__ __bf16 Ks[64 * 72];     // K tile [j][d], rows padded to 72
    __shared__ __bf16 Vs[64 * 72];     // V^T tile [d][j]
    __shared__ __bf16 Ps[4][16 * 72];  // per-wave P round-trip

    bf16x8 aQ0, aQ1;
    {
        const __bf16* qb = q + ((size_t)bh * 1024 + q0 + l16) * 64 + quad * 8;
        aQ0 = *(const bf16x8*)qb;
        aQ1 = *(const bf16x8*)(qb + 32);
    }
    f32x4 o[4] = {};
    float m_i[4], l_i[4];
    #pragma unroll
    for (int r = 0; r < 4; r++) { m_i[r] = -INFINITY; l_i[r] = 0.0f; }

    for (int jb = 0; jb < 1024; jb += 64) {
        __syncthreads();
        #pragma unroll
        for (int it = 0; it < 2; ++it) {
            int c = threadIdx.x + it * 256;
            int row = c >> 3, col = (c & 7) << 3;
            *(bf16x8*)&Ks[row * 72 + col] = *(const bf16x8*)&k [((size_t)bh * 1024 + jb + row) * 64 + col];
            *(bf16x8*)&Vs[row * 72 + col] = *(const bf16x8*)&vt[((size_t)bh * 64 + row) * 1024 + jb + col];
        }
        __syncthreads();

        f32x4 s[4] = {};
        #pragma unroll
        for (int nt = 0; nt < 4; nt++) {
            bf16x8 b0 = *(bf16x8*)&Ks[(nt * 16 + l16) * 72 + quad * 8];
            bf16x8 b1 = *(bf16x8*)&Ks[(nt * 16 + l16) * 72 + 32 + quad * 8];
            s[nt] = __builtin_amdgcn_mfma_f32_16x16x32_bf16(aQ0, b0, s[nt], 0, 0, 0);
            s[nt] = __builtin_amdgcn_mfma_f32_16x16x32_bf16(aQ1, b1, s[nt], 0, 0, 0);
        }
        // additive mask (scale already folded into q)
        const float* mr = tmask + (size_t)bh * 1024 * 1024 + (size_t)(q0 + quad * 4) * 1024 + jb + l16;
        #pragma unroll
        for (int r = 0; r < 4; r++)
            #pragma unroll
            for (int nt = 0; nt < 4; nt++)
                s[nt][r] += mr[(size_t)r * 1024 + nt * 16];

        float alpha[4];
        #pragma unroll
        for (int r = 0; r < 4; r++) {
            float mx = fmaxf(fmaxf(s[0][r], s[1][r]), fmaxf(s[2][r], s[3][r]));
            mx = fmaxf(mx, __shfl_xor(mx, 1));
            mx = fmaxf(mx, __shfl_xor(mx, 2));
            mx = fmaxf(mx, __shfl_xor(mx, 4));
            mx = fmaxf(mx, __shfl_xor(mx, 8));
            float mn = fmaxf(m_i[r], mx);
            alpha[r] = __expf(m_i[r] - mn);
            m_i[r] = mn;
            float rs = 0.0f;
            #pragma unroll
            for (int nt = 0; nt < 4; nt++) {
                float p = __expf(s[nt][r] - mn);
                s[nt][r] = p;
                rs += p;
            }
            rs += __shfl_xor(rs, 1);
            rs += __shfl_xor(rs, 2);
            rs += __shfl_xor(rs, 4);
            rs += __shfl_xor(rs, 8);
            l_i[r] = l_i[r] * alpha[r] + rs;
        }
        #pragma unroll
        for (int dt = 0; dt < 4; dt++)
            #pragma unroll
            for (int r = 0; r < 4; r++) o[dt][r] *= alpha[r];

        // P (C-layout) -> LDS -> A-layout frags (wave-local; LDS ops in-order per wave)
        __bf16* ps = Ps[w];
        #pragma unroll
        for (int nt = 0; nt < 4; nt++)
            #pragma unroll
            for (int r = 0; r < 4; r++)
                ps[(quad * 4 + r) * 72 + nt * 16 + l16] = (__bf16)s[nt][r];
        bf16x8 aP0 = *(bf16x8*)&ps[l16 * 72 + quad * 8];
        bf16x8 aP1 = *(bf16x8*)&ps[l16 * 72 + 32 + quad * 8];
        #pragma unroll
        for (int dt = 0; dt < 4; dt++) {
            bf16x8 bv0 = *(bf16x8*)&Vs[(dt * 16 + l16) * 72 + quad * 8];
            bf16x8 bv1 = *(bf16x8*)&Vs[(dt * 16 + l16) * 72 + 32 + quad * 8];
            o[dt] = __builtin_amdgcn_mfma_f32_16x16x32_bf16(aP0, bv0, o[dt], 0, 0, 0);
            o[dt] = __builtin_amdgcn_mfma_f32_16x16x32_bf16(aP1, bv1, o[dt], 0, 0, 0);
        }
    }

    int b = bh >> 3, h = bh & 7;
    #pragma unroll
    for (int dt = 0; dt < 4; dt++)
        #pragma unroll
        for (int r = 0; r < 4; r++) {
            float v = o[dt][r] / l_i[r];
            ctx[((size_t)b * 1024 + q0 + quad * 4 + r) * 512 + h * 64 + dt * 16 + l16] = (__bf16)v;
        }
}

// ---------------- group attention (seq len 8) : one thread per (t,h,bq) ----------------
__global__ __launch_bounds__(256) void group_attn(
    const __bf16* __restrict__ qg, const __bf16* __restrict__ kg,
    const __bf16* __restrict__ vg, const float* __restrict__ gmask,
    __bf16* __restrict__ ctxg)
{
    int tid = blockIdx.x * 256 + threadIdx.x;
    int t = tid >> 6, h = (tid >> 3) & 7, bq = tid & 7;
    size_t base = ((size_t)t * 8 + h) * 512;   // (t,h) block: 8 rows x 64

    float qv[64];
    #pragma unroll
    for (int d0 = 0; d0 < 64; d0 += 8) {
        bf16x8 qq = *(const bf16x8*)&qg[base + (size_t)bq * 64 + d0];
        #pragma unroll
        for (int u = 0; u < 8; u++) qv[d0 + u] = (float)qq[u];
    }
    float s[8];
    #pragma unroll
    for (int j = 0; j < 8; j++) {
        float acc = 0.0f;
        #pragma unroll
        for (int d0 = 0; d0 < 64; d0 += 8) {
            bf16x8 kk = *(const bf16x8*)&kg[base + (size_t)j * 64 + d0];
            #pragma unroll
            for (int u = 0; u < 8; u++) acc += qv[d0 + u] * (float)kk[u];
        }
        s[j] = acc + gmask[(((size_t)t * 8 + h) * 8 + bq) * 8 + j];
    }
    float mx = s[0];
    #pragma unroll
    for (int j = 1; j < 8; j++) mx = fmaxf(mx, s[j]);
    float sum = 0.0f;
    #pragma unroll
    for (int j = 0; j < 8; j++) { s[j] = __expf(s[j] - mx); sum += s[j]; }
    float inv = 1.0f / sum;

    #pragma unroll
    for (int d0 = 0; d0 < 64; d0 += 8) {
        float o8[8] = {};
        #pragma unroll
        for (int j = 0; j < 8; j++) {
            bf16x8 vv = *(const bf16x8*)&vg[base + (size_t)j * 64 + d0];
            float pj = s[j];
            #pragma unroll
            for (int u = 0; u < 8; u++) o8[u] += pj * (float)vv[u];
        }
        bf16x8 ob;
        #pragma unroll
        for (int u = 0; u < 8; u++) ob[u] = (__bf16)(o8[u] * inv);
        *(bf16x8*)&ctxg[((size_t)t * 8 + bq) * 512 + h * 64 + d0] = ob;
    }
}

extern "C" void kernel_launch(void* const* d_in, const int* in_sizes, int n_in,
                              void* d_out, int out_size, void* d_ws, size_t ws_size,
                              hipStream_t stream)
{
    const float* h      = (const float*)d_in[0];
    const int*   pos    = (const int*)  d_in[1];
    const float* t_mask = (const float*)d_in[2];
    const float* g_mask = (const float*)d_in[3];
    const float* ln_t_w = (const float*)d_in[4];
    const float* ln_g_w = (const float*)d_in[5];
    const float* wq_t = (const float*)d_in[6];
    const float* wk_t = (const float*)d_in[7];
    const float* wv_t = (const float*)d_in[8];
    const float* wo_t = (const float*)d_in[9];
    const float* wq_g = (const float*)d_in[10];
    const float* wk_g = (const float*)d_in[11];
    const float* wv_g = (const float*)d_in[12];
    const float* wo_g = (const float*)d_in[13];
    float* out = (float*)d_out;

    char* ws = (char*)d_ws;
    const size_t MB = 1ull << 20;
    __bf16* qkvT_t = (__bf16*)ws;
    __bf16* oT_t   = qkvT_t + 786432;
    __bf16* qkvT_g = qkvT_t + 1048576;
    __bf16* oT_g   = qkvT_t + 1835008;
    __bf16* normed = (__bf16*)(ws + 4 * MB);
    __bf16* qb     = (__bf16*)(ws + 12 * MB);
    __bf16* kb     = (__bf16*)(ws + 20 * MB);
    __bf16* vb     = (__bf16*)(ws + 28 * MB);
    __bf16* ctx    = (__bf16*)(ws + 36 * MB);
    float*  h2     = (float*) (ws + 44 * MB);

    // weights -> bf16 transposed
    transpose_w<<<dim3(16, 16, 8), 256, 0, stream>>>(
        wq_t, wk_t, wv_t, wo_t, wq_g, wk_g, wv_g, wo_g,
        qkvT_t, oT_t, qkvT_g, oT_g);

    // ---- stage 1: time attention ----
    rmsnorm_k<<<2048, 256, 0, stream>>>(h, ln_t_w, normed, 0);
    gemm_ep<<<dim3(12, 64), 256, 0, stream>>>(normed, qkvT_t, pos, nullptr, nullptr,
                                              qb, kb, vb, 0);
    flash_t<<<dim3(16, 64), 256, 0, stream>>>(qb, kb, vb, t_mask, ctx);
    gemm_ep<<<dim3(4, 64), 256, 0, stream>>>(ctx, oT_t, nullptr, h, h2,
                                             nullptr, nullptr, nullptr, 1);

    // ---- stage 2: group attention (rows remapped to (t,b) order) ----
    rmsnorm_k<<<2048, 256, 0, stream>>>(h2, ln_g_w, normed, 1);
    gemm_ep<<<dim3(12, 64), 256, 0, stream>>>(normed, qkvT_g, nullptr, nullptr, nullptr,
                                              qb, kb, vb, 2);
    group_attn<<<256, 256, 0, stream>>>(qb, kb, vb, g_mask, ctx);
    gemm_ep<<<dim3(4, 64), 256, 0, stream>>>(ctx, oT_g, nullptr, h2, out,
                                             nullptr, nullptr, nullptr, 3);
}

// Round 2
// 542.246 us; speedup vs baseline: 1.0417x; 1.0417x over previous
//
#include <hip/hip_runtime.h>
#include <hip/hip_bf16.h>
#include <math.h>

// Dual-attention block, bf16 MFMA implementation. R2:
//  - GEMM staging via __builtin_amdgcn_global_load_lds width=16 (m97 ladder step)
//  - V^T epilogue scatter replaced by LDS-bounce transpose + 16B stores
//  - sincosf -> __sincosf in RoPE epilogue

typedef __bf16 bf16x8 __attribute__((ext_vector_type(8)));
typedef __bf16 bf16x4 __attribute__((ext_vector_type(4)));
typedef float  f32x4  __attribute__((ext_vector_type(4)));

#define LN1E4_OVER_32 0.2878231366242558f

__device__ __forceinline__ void gld16(const void* g, void* l) {
    __builtin_amdgcn_global_load_lds((const __attribute__((address_space(1))) void*)g,
                                     (__attribute__((address_space(3))) void*)l,
                                     16, 0, 0);
}

// ---------------- weight convert + transpose: wt[n][k] = w[k][n] (bf16) ----------------
__global__ __launch_bounds__(256) void transpose_w(
    const float* w0, const float* w1, const float* w2, const float* w3,
    const float* w4, const float* w5, const float* w6, const float* w7,
    __bf16* qkvT_t, __bf16* oT_t, __bf16* qkvT_g, __bf16* oT_g)
{
    int mat = blockIdx.z;
    const float* src; __bf16* dst; int rowOff;
    switch (mat) {
        case 0: src=w0; dst=qkvT_t; rowOff=0;    break;
        case 1: src=w1; dst=qkvT_t; rowOff=512;  break;
        case 2: src=w2; dst=qkvT_t; rowOff=1024; break;
        case 3: src=w3; dst=oT_t;   rowOff=0;    break;
        case 4: src=w4; dst=qkvT_g; rowOff=0;    break;
        case 5: src=w5; dst=qkvT_g; rowOff=512;  break;
        case 6: src=w6; dst=qkvT_g; rowOff=1024; break;
        default: src=w7; dst=oT_g;  rowOff=0;    break;
    }
    __shared__ float tile[32][33];
    int n0 = blockIdx.x * 32, k0 = blockIdx.y * 32;
    int tt = threadIdx.x;
    int kr = tt >> 3, nc = (tt & 7) * 4;
    float4 v = *(const float4*)(src + (size_t)(k0 + kr) * 512 + n0 + nc);
    tile[kr][nc+0] = v.x; tile[kr][nc+1] = v.y; tile[kr][nc+2] = v.z; tile[kr][nc+3] = v.w;
    __syncthreads();
    int nr = tt >> 3, kc = (tt & 7) * 4;
    bf16x4 o;
    o[0] = (__bf16)tile[kc+0][nr]; o[1] = (__bf16)tile[kc+1][nr];
    o[2] = (__bf16)tile[kc+2][nr]; o[3] = (__bf16)tile[kc+3][nr];
    *(bf16x4*)(dst + (size_t)(rowOff + n0 + nr) * 512 + k0 + kc) = o;
}

// ---------------- RMSNorm rows of 512, fp32 in -> bf16 out; optional (b,t)->(t,b) remap ----------------
__global__ __launch_bounds__(256) void rmsnorm_k(
    const float* __restrict__ x, const float* __restrict__ w,
    __bf16* __restrict__ y, int remap)
{
    int row = blockIdx.x * 4 + (threadIdx.x >> 6);
    int l = threadIdx.x & 63;
    const float* xr = x + (size_t)row * 512 + l * 8;
    float4 a = *(const float4*)xr;
    float4 b = *(const float4*)(xr + 4);
    float ss = a.x*a.x + a.y*a.y + a.z*a.z + a.w*a.w
             + b.x*b.x + b.y*b.y + b.z*b.z + b.w*b.w;
    for (int m = 1; m < 64; m <<= 1) ss += __shfl_xor(ss, m);
    float rms = rsqrtf(ss * (1.0f / 512.0f) + 1e-6f);
    float4 wa = *(const float4*)(w + l * 8);
    float4 wb = *(const float4*)(w + l * 8 + 4);
    int orow = remap ? ((row & 1023) * 8 + (row >> 10)) : row;
    bf16x8 o;
    o[0] = (__bf16)(a.x * rms * wa.x); o[1] = (__bf16)(a.y * rms * wa.y);
    o[2] = (__bf16)(a.z * rms * wa.z); o[3] = (__bf16)(a.w * rms * wa.w);
    o[4] = (__bf16)(b.x * rms * wb.x); o[5] = (__bf16)(b.y * rms * wb.y);
    o[6] = (__bf16)(b.z * rms * wb.z); o[7] = (__bf16)(b.w * rms * wb.w);
    *(bf16x8*)(y + (size_t)orow * 512 + l * 8) = o;
}

// ---------------- 128x128 bf16 MFMA GEMM with fused epilogues ----------------
// mode 0: QKV time  — RoPE on q,k (q *= 0.125), q/k[bh][t][d]; vt[bh][d][t] via LDS bounce
// mode 1: O time    — out fp32 = acc + resid (rows direct)
// mode 2: QKV group — scatter q/k/v [t][h][b][d] (q *= 0.125)
// mode 3: O group   — rows m=(t,b) remapped to (b,t) for resid/out
__global__ __launch_bounds__(256) void gemm_ep(
    const __bf16* __restrict__ A, const __bf16* __restrict__ Bt,
    const int* __restrict__ pos, const float* __restrict__ resid,
    float* __restrict__ outF,
    __bf16* __restrict__ o0, __bf16* __restrict__ o1, __bf16* __restrict__ o2,
    int mode)
{
    __shared__ __bf16 smem[8192];      // As[128*32] | Bs[128*32]; reused as V-bounce
    __bf16* As = smem;
    __bf16* Bs = smem + 4096;
    int tid = threadIdx.x;
    int l = tid & 63, w = tid >> 6;
    int l16 = l & 15, quad = l >> 4;
    int wm = w >> 1, wn = w & 1;
    int mblk = blockIdx.y * 128, nblk = blockIdx.x * 128;
    f32x4 acc[4][4] = {};

    for (int k0 = 0; k0 < 512; k0 += 32) {
        __syncthreads();
        #pragma unroll
        for (int i = 0; i < 2; ++i) {
            int idx = i * 256 + tid;
            int row = idx >> 2, c8 = (idx & 3) * 8;
            gld16(A  + (size_t)(mblk + row) * 512 + k0 + c8, (char*)As + (size_t)idx * 16);
            gld16(Bt + (size_t)(nblk + row) * 512 + k0 + c8, (char*)Bs + (size_t)idx * 16);
        }
        __syncthreads();
        bf16x8 aF[4], bF[4];
        #pragma unroll
        for (int mt = 0; mt < 4; mt++) aF[mt] = *(bf16x8*)(As + (wm * 64 + mt * 16 + l16) * 32 + quad * 8);
        #pragma unroll
        for (int nt = 0; nt < 4; nt++) bF[nt] = *(bf16x8*)(Bs + (wn * 64 + nt * 16 + l16) * 32 + quad * 8);
        #pragma unroll
        for (int mt = 0; mt < 4; mt++)
            #pragma unroll
            for (int nt = 0; nt < 4; nt++)
                acc[mt][nt] = __builtin_amdgcn_mfma_f32_16x16x32_bf16(aF[mt], bF[nt], acc[mt][nt], 0, 0, 0);
    }
    __syncthreads();   // protect smem reuse by V-bounce epilogue

    int colbase = nblk + wn * 64;   // 64-aligned -> wave covers exactly one head of one matrix
    if (mode == 0 || mode == 2) {
        int mat = colbase >> 9;             // 0=q 1=k 2=v (uniform)
        int hh  = (colbase & 511) >> 6;     // head (uniform)
        __bf16* dst = (mat == 0) ? o0 : (mat == 1) ? o1 : o2;
        bool isQ = (mat == 0), isV = (mat == 2);
        if (mode == 0 && isV) {
            // V^T via LDS bounce: per mt-chunk [16 t][64 d] -> vt[bh][d][t], 16B stores
            __bf16* vls = smem + (size_t)w * 1536;   // [64 d][24 pad] per wave
            #pragma unroll
            for (int mt = 0; mt < 4; mt++) {
                #pragma unroll
                for (int nt = 0; nt < 4; nt++)
                    #pragma unroll
                    for (int r = 0; r < 4; r++)
                        vls[(nt * 16 + l16) * 24 + quad * 4 + r] = (__bf16)acc[mt][nt][r];
                int grow0 = mblk + wm * 64 + mt * 16;   // 16 consecutive t, same b
                int b = grow0 >> 10, t0 = grow0 & 1023;
                #pragma unroll
                for (int i = 0; i < 2; ++i) {
                    int li = i * 64 + l;
                    int d = li >> 1, t8 = (li & 1) * 8;
                    bf16x8 vv = *(bf16x8*)&vls[d * 24 + t8];
                    *(bf16x8*)&dst[((size_t)(b * 8 + hh) * 64 + d) * 1024 + t0 + t8] = vv;
                }
            }
        } else {
            #pragma unroll
            for (int mt = 0; mt < 4; mt++) {
                #pragma unroll
                for (int r = 0; r < 4; r++) {
                    int grow = mblk + wm * 64 + mt * 16 + quad * 4 + r;
                    if (mode == 0) {
                        int b = grow >> 10, t = grow & 1023;
                        int p = pos[grow];
                        #pragma unroll
                        for (int nt = 0; nt < 2; nt++) {
                            int i = nt * 16 + l16;                  // d%32
                            float ang = (float)p * __expf((float)i * -LN1E4_OVER_32);
                            float c, s; __sincosf(ang, &s, &c);
                            float x1 = acc[mt][nt][r], x2 = acc[mt][nt + 2][r];
                            float y1 = x1 * c - x2 * s;
                            float y2 = x2 * c + x1 * s;
                            if (isQ) { y1 *= 0.125f; y2 *= 0.125f; }
                            size_t base = ((size_t)(b * 8 + hh) * 1024 + t) * 64;
                            dst[base + i]      = (__bf16)y1;
                            dst[base + i + 32] = (__bf16)y2;
                        }
                    } else { // mode 2
                        int t = grow >> 3, b = grow & 7;
                        size_t base = (((size_t)t * 8 + hh) * 8 + b) * 64;
                        #pragma unroll
                        for (int nt = 0; nt < 4; nt++) {
                            float v = acc[mt][nt][r];
                            if (isQ) v *= 0.125f;
                            dst[base + nt * 16 + l16] = (__bf16)v;
                        }
                    }
                }
            }
        }
    } else { // mode 1 / 3: O-projection + residual, fp32 out
        #pragma unroll
        for (int mt = 0; mt < 4; mt++)
            #pragma unroll
            for (int r = 0; r < 4; r++) {
                int grow = mblk + wm * 64 + mt * 16 + quad * 4 + r;
                int orow = (mode == 3) ? (((grow & 7) << 10) + (grow >> 3)) : grow;
                #pragma unroll
                for (int nt = 0; nt < 4; nt++) {
                    int col = colbase + nt * 16 + l16;
                    size_t oi = (size_t)orow * 512 + col;
                    outF[oi] = acc[mt][nt][r] + resid[oi];
                }
            }
    }
}

// ---------------- flash attention (time axis): per block 64 q-rows of one (b,h) ----------------
__global__ __launch_bounds__(256) void flash_t(
    const __bf16* __restrict__ q, const __bf16* __restrict__ k,
    const __bf16* __restrict__ vt, const float* __restrict__ tmask,
    __bf16* __restrict__ ctx)
{
    int bh = blockIdx.y;
    int w = threadIdx.x >> 6, l = threadIdx.x & 63;
    int l16 = l & 15, quad = l >> 4;
    int q0 = blockIdx.x * 64 + w * 16;

    __shared__ __bf16 Ks[64 * 72];     // K tile [j][d], rows padded to 72
    __shared__ __bf16 Vs[64 * 72];     // V^T tile [d][j]
    __shared__ __bf16 Ps[4][16 * 72];  // per-wave P round-trip

    bf16x8 aQ0, aQ1;
    {
        const __bf16* qb = q + ((size_t)bh * 1024 + q0 + l16) * 64 + quad * 8;
        aQ0 = *(const bf16x8*)qb;
        aQ1 = *(const bf16x8*)(qb + 32);
    }
    f32x4 o[4] = {};
    float m_i[4], l_i[4];
    #pragma unroll
    for (int r = 0; r < 4; r++) { m_i[r] = -INFINITY; l_i[r] = 0.0f; }

    for (int jb = 0; jb < 1024; jb += 64) {
        __syncthreads();
        #pragma unroll
        for (int it = 0; it < 2; ++it) {
            int c = threadIdx.x + it * 256;
            int row = c >> 3, col = (c & 7) << 3;
            *(bf16x8*)&Ks[row * 72 + col] = *(const bf16x8*)&k [((size_t)bh * 1024 + jb + row) * 64 + col];
            *(bf16x8*)&Vs[row * 72 + col] = *(const bf16x8*)&vt[((size_t)bh * 64 + row) * 1024 + jb + col];
        }
        __syncthreads();

        f32x4 s[4] = {};
        #pragma unroll
        for (int nt = 0; nt < 4; nt++) {
            bf16x8 b0 = *(bf16x8*)&Ks[(nt * 16 + l16) * 72 + quad * 8];
            bf16x8 b1 = *(bf16x8*)&Ks[(nt * 16 + l16) * 72 + 32 + quad * 8];
            s[nt] = __builtin_amdgcn_mfma_f32_16x16x32_bf16(aQ0, b0, s[nt], 0, 0, 0);
            s[nt] = __builtin_amdgcn_mfma_f32_16x16x32_bf16(aQ1, b1, s[nt], 0, 0, 0);
        }
        // additive mask (scale already folded into q)
        const float* mr = tmask + (size_t)bh * 1024 * 1024 + (size_t)(q0 + quad * 4) * 1024 + jb + l16;
        #pragma unroll
        for (int r = 0; r < 4; r++)
            #pragma unroll
            for (int nt = 0; nt < 4; nt++)
                s[nt][r] += mr[(size_t)r * 1024 + nt * 16];

        float alpha[4];
        #pragma unroll
        for (int r = 0; r < 4; r++) {
            float mx = fmaxf(fmaxf(s[0][r], s[1][r]), fmaxf(s[2][r], s[3][r]));
            mx = fmaxf(mx, __shfl_xor(mx, 1));
            mx = fmaxf(mx, __shfl_xor(mx, 2));
            mx = fmaxf(mx, __shfl_xor(mx, 4));
            mx = fmaxf(mx, __shfl_xor(mx, 8));
            float mn = fmaxf(m_i[r], mx);
            alpha[r] = __expf(m_i[r] - mn);
            m_i[r] = mn;
            float rs = 0.0f;
            #pragma unroll
            for (int nt = 0; nt < 4; nt++) {
                float p = __expf(s[nt][r] - mn);
                s[nt][r] = p;
                rs += p;
            }
            rs += __shfl_xor(rs, 1);
            rs += __shfl_xor(rs, 2);
            rs += __shfl_xor(rs, 4);
            rs += __shfl_xor(rs, 8);
            l_i[r] = l_i[r] * alpha[r] + rs;
        }
        #pragma unroll
        for (int dt = 0; dt < 4; dt++)
            #pragma unroll
            for (int r = 0; r < 4; r++) o[dt][r] *= alpha[r];

        // P (C-layout) -> LDS -> A-layout frags (wave-local; LDS ops in-order per wave)
        __bf16* ps = Ps[w];
        #pragma unroll
        for (int nt = 0; nt < 4; nt++)
            #pragma unroll
            for (int r = 0; r < 4; r++)
                ps[(quad * 4 + r) * 72 + nt * 16 + l16] = (__bf16)s[nt][r];
        bf16x8 aP0 = *(bf16x8*)&ps[l16 * 72 + quad * 8];
        bf16x8 aP1 = *(bf16x8*)&ps[l16 * 72 + 32 + quad * 8];
        #pragma unroll
        for (int dt = 0; dt < 4; dt++) {
            bf16x8 bv0 = *(bf16x8*)&Vs[(dt * 16 + l16) * 72 + quad * 8];
            bf16x8 bv1 = *(bf16x8*)&Vs[(dt * 16 + l16) * 72 + 32 + quad * 8];
            o[dt] = __builtin_amdgcn_mfma_f32_16x16x32_bf16(aP0, bv0, o[dt], 0, 0, 0);
            o[dt] = __builtin_amdgcn_mfma_f32_16x16x32_bf16(aP1, bv1, o[dt], 0, 0, 0);
        }
    }

    int b = bh >> 3, h = bh & 7;
    #pragma unroll
    for (int dt = 0; dt < 4; dt++)
        #pragma unroll
        for (int r = 0; r < 4; r++) {
            float v = o[dt][r] / l_i[r];
            ctx[((size_t)b * 1024 + q0 + quad * 4 + r) * 512 + h * 64 + dt * 16 + l16] = (__bf16)v;
        }
}

// ---------------- group attention (seq len 8) : one thread per (t,h,bq) ----------------
__global__ __launch_bounds__(256) void group_attn(
    const __bf16* __restrict__ qg, const __bf16* __restrict__ kg,
    const __bf16* __restrict__ vg, const float* __restrict__ gmask,
    __bf16* __restrict__ ctxg)
{
    int tid = blockIdx.x * 256 + threadIdx.x;
    int t = tid >> 6, h = (tid >> 3) & 7, bq = tid & 7;
    size_t base = ((size_t)t * 8 + h) * 512;   // (t,h) block: 8 rows x 64

    float qv[64];
    #pragma unroll
    for (int d0 = 0; d0 < 64; d0 += 8) {
        bf16x8 qq = *(const bf16x8*)&qg[base + (size_t)bq * 64 + d0];
        #pragma unroll
        for (int u = 0; u < 8; u++) qv[d0 + u] = (float)qq[u];
    }
    float s[8];
    #pragma unroll
    for (int j = 0; j < 8; j++) {
        float acc = 0.0f;
        #pragma unroll
        for (int d0 = 0; d0 < 64; d0 += 8) {
            bf16x8 kk = *(const bf16x8*)&kg[base + (size_t)j * 64 + d0];
            #pragma unroll
            for (int u = 0; u < 8; u++) acc += qv[d0 + u] * (float)kk[u];
        }
        s[j] = acc + gmask[(((size_t)t * 8 + h) * 8 + bq) * 8 + j];
    }
    float mx = s[0];
    #pragma unroll
    for (int j = 1; j < 8; j++) mx = fmaxf(mx, s[j]);
    float sum = 0.0f;
    #pragma unroll
    for (int j = 0; j < 8; j++) { s[j] = __expf(s[j] - mx); sum += s[j]; }
    float inv = 1.0f / sum;

    #pragma unroll
    for (int d0 = 0; d0 < 64; d0 += 8) {
        float o8[8] = {};
        #pragma unroll
        for (int j = 0; j < 8; j++) {
            bf16x8 vv = *(const bf16x8*)&vg[base + (size_t)j * 64 + d0];
            float pj = s[j];
            #pragma unroll
            for (int u = 0; u < 8; u++) o8[u] += pj * (float)vv[u];
        }
        bf16x8 ob;
        #pragma unroll
        for (int u = 0; u < 8; u++) ob[u] = (__bf16)(o8[u] * inv);
        *(bf16x8*)&ctxg[((size_t)t * 8 + bq) * 512 + h * 64 + d0] = ob;
    }
}

extern "C" void kernel_launch(void* const* d_in, const int* in_sizes, int n_in,
                              void* d_out, int out_size, void* d_ws, size_t ws_size,
                              hipStream_t stream)
{
    const float* h      = (const float*)d_in[0];
    const int*   pos    = (const int*)  d_in[1];
    const float* t_mask = (const float*)d_in[2];
    const float* g_mask = (const float*)d_in[3];
    const float* ln_t_w = (const float*)d_in[4];
    const float* ln_g_w = (const float*)d_in[5];
    const float* wq_t = (const float*)d_in[6];
    const float* wk_t = (const float*)d_in[7];
    const float* wv_t = (const float*)d_in[8];
    const float* wo_t = (const float*)d_in[9];
    const float* wq_g = (const float*)d_in[10];
    const float* wk_g = (const float*)d_in[11];
    const float* wv_g = (const float*)d_in[12];
    const float* wo_g = (const float*)d_in[13];
    float* out = (float*)d_out;

    char* ws = (char*)d_ws;
    const size_t MB = 1ull << 20;
    __bf16* qkvT_t = (__bf16*)ws;
    __bf16* oT_t   = qkvT_t + 786432;
    __bf16* qkvT_g = qkvT_t + 1048576;
    __bf16* oT_g   = qkvT_t + 1835008;
    __bf16* normed = (__bf16*)(ws + 4 * MB);
    __bf16* qb     = (__bf16*)(ws + 12 * MB);
    __bf16* kb     = (__bf16*)(ws + 20 * MB);
    __bf16* vb     = (__bf16*)(ws + 28 * MB);
    __bf16* ctx    = (__bf16*)(ws + 36 * MB);
    float*  h2     = (float*) (ws + 44 * MB);

    // weights -> bf16 transposed
    transpose_w<<<dim3(16, 16, 8), 256, 0, stream>>>(
        wq_t, wk_t, wv_t, wo_t, wq_g, wk_g, wv_g, wo_g,
        qkvT_t, oT_t, qkvT_g, oT_g);

    // ---- stage 1: time attention ----
    rmsnorm_k<<<2048, 256, 0, stream>>>(h, ln_t_w, normed, 0);
    gemm_ep<<<dim3(12, 64), 256, 0, stream>>>(normed, qkvT_t, pos, nullptr, nullptr,
                                              qb, kb, vb, 0);
    flash_t<<<dim3(16, 64), 256, 0, stream>>>(qb, kb, vb, t_mask, ctx);
    gemm_ep<<<dim3(4, 64), 256, 0, stream>>>(ctx, oT_t, nullptr, h, h2,
                                             nullptr, nullptr, nullptr, 1);

    // ---- stage 2: group attention (rows remapped to (t,b) order) ----
    rmsnorm_k<<<2048, 256, 0, stream>>>(h2, ln_g_w, normed, 1);
    gemm_ep<<<dim3(12, 64), 256, 0, stream>>>(normed, qkvT_g, nullptr, nullptr, nullptr,
                                              qb, kb, vb, 2);
    group_attn<<<256, 256, 0, stream>>>(qb, kb, vb, g_mask, ctx);
    gemm_ep<<<dim3(4, 64), 256, 0, stream>>>(ctx, oT_g, nullptr, h2, out,
                                             nullptr, nullptr, nullptr, 3);
}